// Round 1
// baseline (222.889 us; speedup 1.0000x reference)
//
#include <hip/hip_runtime.h>
#include <math.h>

// Sobel gradient magnitude, zero-padded 3x3 cross stencil.
// x: [8, 64, 256, 256] f32 -> out same shape.
// gv = x[i+1,j] - x[i-1,j]; gh = x[i,j+1] - x[i,j-1]; out = sqrt(gv^2+gh^2+eps)
//
// v2: two output rows per thread (rows r, r+1 from loads of rows r-1..r+2),
//     horizontal neighbors via wave shuffles (a row of 256 floats = 64 float4
//     lanes = exactly one wave), nontemporal output stores so the write
//     stream does not evict the input from L2/L3.

#define PLANE_H 256
#define PLANE_W 256
#define VECW 64   // PLANE_W / 4

typedef float f32x4_t __attribute__((ext_vector_type(4)));

__device__ __forceinline__ void nt_store_f4(float* p, float4 v) {
    __builtin_nontemporal_store(*(const f32x4_t*)&v, (f32x4_t*)p);
}

__global__ __launch_bounds__(256) void sobel_kernel(const float* __restrict__ x,
                                                    float* __restrict__ out,
                                                    int total_threads) {
    int idx = blockIdx.x * blockDim.x + threadIdx.x;
    if (idx >= total_threads) return;

    int lane  = idx & (VECW - 1);          // vec-column within row == hw lane
    int rp    = (idx >> 6) & 127;          // row-pair within plane (128 pairs)
    int plane = idx >> 13;                 // 64*128 = 2^13 threads per plane
    int r     = rp << 1;                   // even base row: 0..254

    size_t base = ((size_t)plane << 16) + ((size_t)r << 8) + ((size_t)lane << 2);
    const float* p = x + base;

    const float4 zero = make_float4(0.f, 0.f, 0.f, 0.f);

    // rows r-1, r, r+1, r+2  (a,b,c,d). Branch predicates are wave-uniform.
    float4 b = *(const float4*)p;
    float4 c = *(const float4*)(p + PLANE_W);
    float4 a = (r > 0)             ? *(const float4*)(p - PLANE_W)     : zero;
    float4 d = (r < PLANE_H - 2)   ? *(const float4*)(p + 2 * PLANE_W) : zero;

    // horizontal neighbors from adjacent lanes (wave = exactly one row)
    float bl = __shfl_up(b.w, 1);   bl = (lane == 0)        ? 0.f : bl;
    float br = __shfl_down(b.x, 1); br = (lane == VECW - 1) ? 0.f : br;
    float cl = __shfl_up(c.w, 1);   cl = (lane == 0)        ? 0.f : cl;
    float cr = __shfl_down(c.x, 1); cr = (lane == VECW - 1) ? 0.f : cr;

    const float eps = 1e-6f;

    // output row r: gh from row b, gv = c - a
    {
        float gh0 = b.y - bl;
        float gh1 = b.z - b.x;
        float gh2 = b.w - b.y;
        float gh3 = br  - b.z;
        float gv0 = c.x - a.x;
        float gv1 = c.y - a.y;
        float gv2 = c.z - a.z;
        float gv3 = c.w - a.w;
        float4 o;
        o.x = sqrtf(gv0 * gv0 + gh0 * gh0 + eps);
        o.y = sqrtf(gv1 * gv1 + gh1 * gh1 + eps);
        o.z = sqrtf(gv2 * gv2 + gh2 * gh2 + eps);
        o.w = sqrtf(gv3 * gv3 + gh3 * gh3 + eps);
        nt_store_f4(out + base, o);
    }

    // output row r+1: gh from row c, gv = d - b
    {
        float gh0 = c.y - cl;
        float gh1 = c.z - c.x;
        float gh2 = c.w - c.y;
        float gh3 = cr  - c.z;
        float gv0 = d.x - b.x;
        float gv1 = d.y - b.y;
        float gv2 = d.z - b.z;
        float gv3 = d.w - b.w;
        float4 o;
        o.x = sqrtf(gv0 * gv0 + gh0 * gh0 + eps);
        o.y = sqrtf(gv1 * gv1 + gh1 * gh1 + eps);
        o.z = sqrtf(gv2 * gv2 + gh2 * gh2 + eps);
        o.w = sqrtf(gv3 * gv3 + gh3 * gh3 + eps);
        nt_store_f4(out + base + PLANE_W, o);
    }
}

extern "C" void kernel_launch(void* const* d_in, const int* in_sizes, int n_in,
                              void* d_out, int out_size, void* d_ws, size_t ws_size,
                              hipStream_t stream) {
    const float* x = (const float*)d_in[0];
    float* out = (float*)d_out;
    int total_threads = out_size / 8;      // one thread per 2 float4s (8 floats)
    int block = 256;
    int grid = (total_threads + block - 1) / block;
    sobel_kernel<<<grid, block, 0, stream>>>(x, out, total_threads);
}